// Round 15
// baseline (529.391 us; speedup 1.0000x reference)
//
#include <hip/hip_runtime.h>
#include <hip/hip_bf16.h>

// MotionTransformer: B=64,S=1024,F=136,D=64,H=2,DH=32,DFF=256,C=2
// out (f32): [logits(128) | attn(134217728)].
// ROUND 15: fa stores attn directly from registers (f32, cached, dense
// 64B-line segments), issued before the pb barrier; LDS store-phase removed;
// f2bf via intrinsic.

typedef unsigned short u16;
typedef short bf16x8 __attribute__((ext_vector_type(8)));
typedef float f32x4 __attribute__((ext_vector_type(4)));

#define DEVI __device__ __forceinline__
#define MFMA __builtin_amdgcn_mfma_f32_16x16x32_bf16

DEVI u16 f2bf(float f) {
  __hip_bfloat16 h = __float2bfloat16(f);
  return *reinterpret_cast<u16*>(&h);
}
DEVI float bf2f(u16 h) {
  union { unsigned u; float f; } v; v.u = ((unsigned)h) << 16;
  return v.f;
}
DEVI float wred_sum(float v) {
#pragma unroll
  for (int off = 32; off; off >>= 1) v += __shfl_xor(v, off);
  return v;
}

// ---- 1: h = x@W_in + b_in + PE. 32 rows/block, 64 thr ----
__global__ __launch_bounds__(64) void r1_inproj(const float* __restrict__ x,
                                                const float* __restrict__ Win,
                                                const float* __restrict__ bin,
                                                float* __restrict__ hf) {
  __shared__ float xs[32][140];
  const int r0 = blockIdx.x * 32, d = threadIdx.x;
  for (int e = d; e < 32 * 136; e += 64) {
    int r = e / 136, k = e - r * 136;
    xs[r][k] = x[(size_t)(r0 + r) * 136 + k];
  }
  __syncthreads();
  float acc[32];
#pragma unroll
  for (int r = 0; r < 32; ++r) acc[r] = 0.f;
  for (int k = 0; k < 136; k += 4) {
    float w0 = Win[(size_t)k * 64 + d];
    float w1 = Win[(size_t)(k + 1) * 64 + d];
    float w2 = Win[(size_t)(k + 2) * 64 + d];
    float w3 = Win[(size_t)(k + 3) * 64 + d];
#pragma unroll
    for (int r = 0; r < 32; ++r) {
      f32x4 xv = *(const f32x4*)&xs[r][k];
      acc[r] = fmaf(xv[0], w0, fmaf(xv[1], w1, fmaf(xv[2], w2, fmaf(xv[3], w3, acc[r]))));
    }
  }
  const float bcol = bin[d];
  const int m = d >> 1;
  const float freq = __expf((float)(2 * m) * -0.14391156831212787f); // -ln(1e4)/64
  const int s0 = r0 & 1023;
#pragma unroll
  for (int r = 0; r < 32; ++r) {
    const float ang = (float)(s0 + r) * freq;
    const float pe = (d & 1) ? cosf(ang) : sinf(ang);
    hf[(size_t)(r0 + r) * 64 + d] = acc[r] + bcol + pe;
  }
}

// ---- 2: qkv -> qH/qL,kH/kL [bh][s][32] ; vtH/vtL [bh][32][1024] (LDS transpose) ----
__global__ __launch_bounds__(192) void r2_qkv(const float* __restrict__ hf,
                                              const float* __restrict__ Wq,
                                              const float* __restrict__ bq,
                                              u16* __restrict__ qH, u16* __restrict__ qL,
                                              u16* __restrict__ kH, u16* __restrict__ kL,
                                              u16* __restrict__ vtH, u16* __restrict__ vtL) {
  __shared__ float hr[32][68];
  __shared__ u16 vbH[64][40];
  __shared__ u16 vbL[64][40];
  const int r0 = blockIdx.x * 32, t = threadIdx.x;
  for (int e = t; e < 2048; e += 192) {
    int r = e >> 6, k = e & 63;
    hr[r][k] = hf[(size_t)(r0 + r) * 64 + k];
  }
  __syncthreads();
  float acc[32];
  const float bias = bq[t];
#pragma unroll
  for (int r = 0; r < 32; ++r) acc[r] = bias;
  for (int k = 0; k < 64; k += 4) {
    float w0 = Wq[(size_t)k * 192 + t];
    float w1 = Wq[(size_t)(k + 1) * 192 + t];
    float w2 = Wq[(size_t)(k + 2) * 192 + t];
    float w3 = Wq[(size_t)(k + 3) * 192 + t];
#pragma unroll
    for (int r = 0; r < 32; ++r) {
      f32x4 hv = *(const f32x4*)&hr[r][k];
      acc[r] = fmaf(hv[0], w0, fmaf(hv[1], w1, fmaf(hv[2], w2, fmaf(hv[3], w3, acc[r]))));
    }
  }
  const int which = t >> 6, c = t & 63, h = c >> 5, dh = c & 31;
  const int b = r0 >> 10, s0 = r0 & 1023;
  const size_t bh = (size_t)(b * 2 + h);
#pragma unroll
  for (int r = 0; r < 32; ++r) {
    const int s = s0 + r;
    u16 hi = f2bf(acc[r]);
    u16 lo = f2bf(acc[r] - bf2f(hi));
    if (which == 0)      { qH[(bh * 1024 + s) * 32 + dh] = hi; qL[(bh * 1024 + s) * 32 + dh] = lo; }
    else if (which == 1) { kH[(bh * 1024 + s) * 32 + dh] = hi; kL[(bh * 1024 + s) * 32 + dh] = lo; }
    else                 { vbH[c][r] = hi; vbL[c][r] = lo; }
  }
  __syncthreads();
  if (t < 128) {
    const int hh = (t & 63) >> 5, dh2 = t & 31;
    const size_t vb = ((size_t)(b * 2 + hh) * 32 + dh2) * 1024 + s0;
    const u16* src = (t < 64) ? &vbH[(t & 63)][0] : &vbL[(t & 63)][0];
    u16* dst = (t < 64) ? vtH : vtL;
#pragma unroll
    for (int i = 0; i < 2; ++i) {
      bf16x8 v = *(const bf16x8*)&src[i * 16];
      bf16x8 w = *(const bf16x8*)&src[i * 16 + 8];
      *(bf16x8*)&dst[vb + i * 16] = v;
      *(bf16x8*)&dst[vb + i * 16 + 8] = w;
    }
  }
}

// ---- 3: FUSED attention, 8 waves/block, XCD-swizzled, direct reg->attn stores ----
__global__ __launch_bounds__(512, 4) void r3_fa(const u16* __restrict__ qH, const u16* __restrict__ qL,
                                                const u16* __restrict__ kH, const u16* __restrict__ kL,
                                                const u16* __restrict__ vtH, const u16* __restrict__ vtL,
                                                float* __restrict__ attn, float* __restrict__ ctx) {
  __shared__ __align__(16) char smem[33792];
  u16* pb = (u16*)smem;                        // [16][1024] bf16 P, swizzled (32 KB)
  float* redm = (float*)(smem + 32768);
  float* reds = (float*)(smem + 33280);
  float* part = (float*)smem;                  // aliased over pb after PV

  const int bid = blockIdx.x;
  const int wid = (bid & 7) * 1024 + (bid >> 3);
  const int bh = wid >> 6, qt = wid & 63;
  const int t = threadIdx.x, lane = t & 63, wv = t >> 6;
  const int fr = lane & 15, rg = lane >> 4, koff = rg * 8;
  const int i0 = qt * 16;
  const float scale = 0.17677669529663687f; // 1/sqrt(32)

  const size_t qoff = ((size_t)bh * 1024 + i0 + fr) * 32 + koff;
  bf16x8 aqh = *(const bf16x8*)&qH[qoff];
  bf16x8 aql = *(const bf16x8*)&qL[qoff];

  // QK^T: wave wv owns k-cols [wv*128, wv*128+128)
  f32x4 s[8];
#pragma unroll
  for (int jl = 0; jl < 8; ++jl) {
    const int jt = wv * 8 + jl;
    const size_t kof = ((size_t)bh * 1024 + jt * 16 + fr) * 32 + koff;
    bf16x8 bkh = *(const bf16x8*)&kH[kof];
    bf16x8 bkl = *(const bf16x8*)&kL[kof];
    f32x4 a = {};
    a = MFMA(aqh, bkh, a, 0, 0, 0);
    a = MFMA(aqh, bkl, a, 0, 0, 0);
    a = MFMA(aql, bkh, a, 0, 0, 0);
#pragma unroll
    for (int r = 0; r < 4; ++r) s[jl][r] = a[r] * scale;
  }

  // split-k softmax across 8 waves
  float m4[4];
#pragma unroll
  for (int r = 0; r < 4; ++r) m4[r] = s[0][r];
#pragma unroll
  for (int jl = 1; jl < 8; ++jl)
#pragma unroll
    for (int r = 0; r < 4; ++r) m4[r] = fmaxf(m4[r], s[jl][r]);
#pragma unroll
  for (int off = 1; off < 16; off <<= 1)
#pragma unroll
    for (int r = 0; r < 4; ++r) m4[r] = fmaxf(m4[r], __shfl_xor(m4[r], off));
  if (fr == 0) {
#pragma unroll
    for (int r = 0; r < 4; ++r) redm[wv * 16 + rg * 4 + r] = m4[r];
  }
  __syncthreads();
  float mg[4];
#pragma unroll
  for (int r = 0; r < 4; ++r) {
    const int row = rg * 4 + r;
    float m = redm[row];
#pragma unroll
    for (int w = 1; w < 8; ++w) m = fmaxf(m, redm[w * 16 + row]);
    mg[r] = m;
  }
  float s4[4] = {0.f, 0.f, 0.f, 0.f};
#pragma unroll
  for (int jl = 0; jl < 8; ++jl)
#pragma unroll
    for (int r = 0; r < 4; ++r) { s[jl][r] = __expf(s[jl][r] - mg[r]); s4[r] += s[jl][r]; }
#pragma unroll
  for (int off = 1; off < 16; off <<= 1)
#pragma unroll
    for (int r = 0; r < 4; ++r) s4[r] += __shfl_xor(s4[r], off);
  if (fr == 0) {
#pragma unroll
    for (int r = 0; r < 4; ++r) reds[wv * 16 + rg * 4 + r] = s4[r];
  }
  __syncthreads();
  float inv[4];
#pragma unroll
  for (int r = 0; r < 4; ++r) {
    const int row = rg * 4 + r;
    float ssum = reds[row];
#pragma unroll
    for (int w = 1; w < 8; ++w) ssum += reds[w * 16 + row];
    inv[r] = 1.f / ssum;
  }

  // normalize: store attn DIRECTLY from registers (f32, cached; per instr
  // 64 lanes = 4 rows x 16 contig cols = 4 full 64B lines), and write bf16
  // P to LDS for PV. Stores issue before the barrier -> overlap with PV.
#pragma unroll
  for (int r = 0; r < 4; ++r) {
    const int row = rg * 4 + r;
    const int sw = rg << 4;
    const int rb = row * 1024;
    const size_t gb = ((size_t)bh * 1024 + i0 + row) * 1024;
#pragma unroll
    for (int jl = 0; jl < 8; ++jl) {
      const int col = (wv * 8 + jl) * 16 + fr;
      const float p = s[jl][r] * inv[r];
      attn[gb + col] = p;
      pb[rb + (col ^ sw)] = f2bf(p);
    }
  }
  __syncthreads();

  // PV: wave wv handles k-tiles wv*4..wv*4+3
  const int sw2 = (fr >> 2) << 4;
  f32x4 acc2[2] = {};
#pragma unroll
  for (int i = 0; i < 4; ++i) {
    const int kt = wv * 4 + i;
    const int cb = kt * 32 + rg * 8;
    bf16x8 ph = *(const bf16x8*)&pb[fr * 1024 + (cb ^ sw2)];
#pragma unroll
    for (int nb = 0; nb < 2; ++nb) {
      const size_t vo = ((size_t)bh * 32 + nb * 16 + fr) * 1024 + cb;
      bf16x8 vh = *(const bf16x8*)&vtH[vo];
      bf16x8 vl = *(const bf16x8*)&vtL[vo];
      acc2[nb] = MFMA(ph, vh, acc2[nb], 0, 0, 0);
      acc2[nb] = MFMA(ph, vl, acc2[nb], 0, 0, 0);
    }
  }
  __syncthreads();
#pragma unroll
  for (int nb = 0; nb < 2; ++nb)
#pragma unroll
    for (int r = 0; r < 4; ++r)
      part[(wv * 16 + rg * 4 + r) * 32 + nb * 16 + fr] = acc2[nb][r];
  __syncthreads();
  const int b = bh >> 1, h = bh & 1;
  {
    const int row = t >> 5, dh = t & 31;
    float v = part[(row) * 32 + dh];
#pragma unroll
    for (int w = 1; w < 8; ++w) v += part[(w * 16 + row) * 32 + dh];
    ctx[((size_t)b * 1024 + i0 + row) * 64 + h * 32 + dh] = v;
  }
}

// ---- 4: FUSED ln1 + FF + ln2 + partial pool. 16 rows/block, 256 thr ----
__global__ __launch_bounds__(256) void r56_ln_ff(const float* __restrict__ ctx,
                                                 const float* __restrict__ Wo,
                                                 const float* __restrict__ bo,
                                                 const float* __restrict__ hf,
                                                 const float* __restrict__ g1,
                                                 const float* __restrict__ be1,
                                                 const float* __restrict__ W1,
                                                 const float* __restrict__ b1,
                                                 const float* __restrict__ W2,
                                                 const float* __restrict__ b2,
                                                 const float* __restrict__ g2,
                                                 const float* __restrict__ be2,
                                                 float* __restrict__ pp) {
  __shared__ __align__(16) char smem[38656];
  float* yr   = (float*)smem;
  float* fr   = (float*)(smem + 4352);
  float* part = (float*)(smem + 21248);
  float* cr   = (float*)(smem + 4352);
  float* wo   = (float*)(smem + 8704);
  float* pw   = (float*)(smem + 37632);
  const int r0 = blockIdx.x * 16;
  const int t = threadIdx.x, d = t & 63, wv = t >> 6;

  for (int e = t; e < 1024; e += 256) cr[(e >> 6) * 68 + (e & 63)] = ctx[(size_t)(r0 + (e >> 6)) * 64 + (e & 63)];
  for (int e = t; e < 4096; e += 256) wo[e] = Wo[e];
  __syncthreads();

  {
    float acc[4];
    const float bias = bo[d];
#pragma unroll
    for (int r = 0; r < 4; ++r) acc[r] = bias;
    for (int k = 0; k < 64; ++k) {
      const float w = wo[k * 64 + d];
#pragma unroll
      for (int r = 0; r < 4; ++r) acc[r] = fmaf(cr[(wv * 4 + r) * 68 + k], w, acc[r]);
    }
    const float gd = g1[d], bd = be1[d];
#pragma unroll
    for (int r = 0; r < 4; ++r) {
      const int row = wv * 4 + r;
      const float rv = hf[(size_t)(r0 + row) * 64 + d] + acc[r];
      const float mu = wred_sum(rv) * (1.f / 64.f);
      const float dd = rv - mu;
      const float var = wred_sum(dd * dd) * (1.f / 64.f);
      yr[row * 68 + d] = dd * rsqrtf(var + 1e-5f) * gd + bd;
    }
  }
  __syncthreads();

  {
    float acc[16];
    const float bias = b1[t];
#pragma unroll
    for (int r = 0; r < 16; ++r) acc[r] = bias;
    for (int k = 0; k < 64; k += 4) {
      float w0 = W1[(size_t)k * 256 + t];
      float w1 = W1[(size_t)(k + 1) * 256 + t];
      float w2 = W1[(size_t)(k + 2) * 256 + t];
      float w3 = W1[(size_t)(k + 3) * 256 + t];
#pragma unroll
      for (int r = 0; r < 16; ++r) {
        f32x4 yv = *(const f32x4*)&yr[r * 68 + k];
        acc[r] = fmaf(yv[0], w0, fmaf(yv[1], w1, fmaf(yv[2], w2, fmaf(yv[3], w3, acc[r]))));
      }
    }
#pragma unroll
    for (int r = 0; r < 16; ++r) fr[r * 264 + t] = fmaxf(acc[r], 0.f);
  }
  __syncthreads();

  {
    float acc[16];
#pragma unroll
    for (int r = 0; r < 16; ++r) acc[r] = 0.f;
    for (int kk = 0; kk < 64; kk += 4) {
      const int k = wv * 64 + kk;
      float w0 = W2[(size_t)k * 64 + d];
      float w1 = W2[(size_t)(k + 1) * 64 + d];
      float w2 = W2[(size_t)(k + 2) * 64 + d];
      float w3 = W2[(size_t)(k + 3) * 64 + d];
#pragma unroll
      for (int r = 0; r < 16; ++r) {
        f32x4 fv = *(const f32x4*)&fr[r * 264 + k];
        acc[r] = fmaf(fv[0], w0, fmaf(fv[1], w1, fmaf(fv[2], w2, fmaf(fv[3], w3, acc[r]))));
      }
    }
#pragma unroll
    for (int r = 0; r < 16; ++r) part[(wv * 16 + r) * 64 + d] = acc[r];
  }
  __syncthreads();

  {
    float pool = 0.f;
    const float bd2 = b2[d], gd = g2[d], bd = be2[d];
#pragma unroll
    for (int rr = 0; rr < 4; ++rr) {
      const int row = wv * 4 + rr;
      const float o2 = part[row * 64 + d] + part[(16 + row) * 64 + d] +
                       part[(32 + row) * 64 + d] + part[(48 + row) * 64 + d] + bd2;
      const float rv = yr[row * 68 + d] + o2;
      const float mu = wred_sum(rv) * (1.f / 64.f);
      const float dd = rv - mu;
      const float var = wred_sum(dd * dd) * (1.f / 64.f);
      pool += dd * rsqrtf(var + 1e-5f) * gd + bd;
    }
    pw[wv * 64 + d] = pool;
  }
  __syncthreads();
  if (t < 64) pp[(size_t)blockIdx.x * 64 + t] = pw[t] + pw[64 + t] + pw[128 + t] + pw[192 + t];
}

// ---- 5: reduce pool partials + classifier -> logits ----
__global__ __launch_bounds__(64) void r7_cls(const float* __restrict__ pp,
                                             const float* __restrict__ Wc1,
                                             const float* __restrict__ bc1,
                                             const float* __restrict__ Wc2,
                                             const float* __restrict__ bc2,
                                             float* __restrict__ outp) {
  const int b = blockIdx.x, d = threadIdx.x;
  float po = 0.f;
  for (int i = 0; i < 64; ++i) po += pp[(size_t)(b * 64 + i) * 64 + d];
  po *= (1.f / 1024.f);
  float acc = bc1[d];
  for (int k = 0; k < 64; ++k) acc = fmaf(__shfl(po, k), Wc1[(size_t)k * 64 + d], acc);
  const float t1 = fmaxf(acc, 0.f);
  const float l0 = wred_sum(t1 * Wc2[(size_t)d * 2 + 0]);
  const float l1 = wred_sum(t1 * Wc2[(size_t)d * 2 + 1]);
  if (d == 0) {
    outp[b * 2 + 0] = l0 + bc2[0];
    outp[b * 2 + 1] = l1 + bc2[1];
  }
}

extern "C" void kernel_launch(void* const* d_in, const int* in_sizes, int n_in,
                              void* d_out, int out_size, void* d_ws, size_t ws_size,
                              hipStream_t stream) {
  (void)in_sizes; (void)n_in; (void)out_size; (void)ws_size;
  const float* x     = (const float*)d_in[0];
  const float* W_in  = (const float*)d_in[1];
  const float* b_in  = (const float*)d_in[2];
  const float* W_qkv = (const float*)d_in[3];
  const float* b_qkv = (const float*)d_in[4];
  const float* W_o   = (const float*)d_in[5];
  const float* b_o   = (const float*)d_in[6];
  const float* g1    = (const float*)d_in[7];
  const float* be1   = (const float*)d_in[8];
  const float* W1    = (const float*)d_in[9];
  const float* b1    = (const float*)d_in[10];
  const float* W2    = (const float*)d_in[11];
  const float* b2    = (const float*)d_in[12];
  const float* g2    = (const float*)d_in[13];
  const float* be2   = (const float*)d_in[14];
  const float* Wc1   = (const float*)d_in[15];
  const float* bc1   = (const float*)d_in[16];
  const float* Wc2   = (const float*)d_in[17];
  const float* bc2   = (const float*)d_in[18];

  char* ws = (char*)d_ws;
  const size_t SZF = (size_t)65536 * 64 * 4;       // 16.78 MB
  const size_t SZH = (size_t)128 * 1024 * 32 * 2;  //  8.39 MB
  float* hf  = (float*)(ws + 0);
  u16* qH    = (u16*)(ws + SZF);
  u16* qL    = (u16*)(ws + SZF + 1 * SZH);
  u16* kH    = (u16*)(ws + SZF + 2 * SZH);
  u16* kL    = (u16*)(ws + SZF + 3 * SZH);
  u16* vtH   = (u16*)(ws + SZF + 4 * SZH);
  u16* vtL   = (u16*)(ws + SZF + 5 * SZH);
  float* ctx = (float*)(ws + SZF + 6 * SZH);
  float* pp  = (float*)(ws + 2 * SZF + 6 * SZH);   // 1 MB

  float* outp = (float*)d_out;       // [logits 128 | attn] f32
  float* attn = outp + 128;

  r1_inproj<<<2048, 64, 0, stream>>>(x, W_in, b_in, hf);
  r2_qkv   <<<2048, 192, 0, stream>>>(hf, W_qkv, b_qkv, qH, qL, kH, kL, vtH, vtL);
  r3_fa    <<<8192, 512, 0, stream>>>(qH, qL, kH, kL, vtH, vtL, attn, ctx);
  r56_ln_ff<<<4096, 256, 0, stream>>>(ctx, W_o, b_o, hf, g1, be1, W1, b1, W2, b2, g2, be2, pp);
  r7_cls   <<<64, 64, 0, stream>>>(pp, Wc1, bc1, Wc2, bc2, outp);
}

// Round 16
// 423.432 us; speedup vs baseline: 1.2502x; 1.2502x over previous
//
#include <hip/hip_runtime.h>

// MotionTransformer: B=64,S=1024,F=136,D=64,H=2,DH=32,DFF=256,C=2
// out (f32): [logits(128) | attn(134217728)].
// ROUND 16: fa reverted to round-14 form (best known). Tail widened:
// r1 256thr (4 waves), r2 384thr (2 row-groups), r7p 256thr parallel reduce.

typedef unsigned short u16;
typedef short bf16x8 __attribute__((ext_vector_type(8)));
typedef short bf16x4 __attribute__((ext_vector_type(4)));
typedef float f32x4 __attribute__((ext_vector_type(4)));

#define DEVI __device__ __forceinline__
#define MFMA __builtin_amdgcn_mfma_f32_16x16x32_bf16

DEVI u16 f2bf(float f) {
  union { float f; unsigned u; } v; v.f = f;
  unsigned r = v.u + 0x7FFFu + ((v.u >> 16) & 1u);
  return (u16)(r >> 16);
}
DEVI float bf2f(u16 h) {
  union { unsigned u; float f; } v; v.u = ((unsigned)h) << 16;
  return v.f;
}
DEVI float wred_sum(float v) {
#pragma unroll
  for (int off = 32; off; off >>= 1) v += __shfl_xor(v, off);
  return v;
}

// ---- 1: h = x@W_in + b_in + PE. 32 rows/block, 256 thr (4 waves x 8 rows) ----
__global__ __launch_bounds__(256) void r1_inproj(const float* __restrict__ x,
                                                 const float* __restrict__ Win,
                                                 const float* __restrict__ bin,
                                                 float* __restrict__ hf) {
  __shared__ float xs[32][140];
  const int r0 = blockIdx.x * 32, t = threadIdx.x;
  const int lane = t & 63, wv = t >> 6;
  for (int e = t; e < 32 * 136; e += 256) {
    int r = e / 136, k = e - r * 136;
    xs[r][k] = x[(size_t)(r0 + r) * 136 + k];
  }
  __syncthreads();
  float acc[8];
#pragma unroll
  for (int r = 0; r < 8; ++r) acc[r] = 0.f;
  for (int k = 0; k < 136; k += 4) {
    float w0 = Win[(size_t)k * 64 + lane];
    float w1 = Win[(size_t)(k + 1) * 64 + lane];
    float w2 = Win[(size_t)(k + 2) * 64 + lane];
    float w3 = Win[(size_t)(k + 3) * 64 + lane];
#pragma unroll
    for (int r = 0; r < 8; ++r) {
      f32x4 xv = *(const f32x4*)&xs[wv * 8 + r][k];
      acc[r] = fmaf(xv[0], w0, fmaf(xv[1], w1, fmaf(xv[2], w2, fmaf(xv[3], w3, acc[r]))));
    }
  }
  const float bcol = bin[lane];
  const int m = lane >> 1;
  const float freq = __expf((float)(2 * m) * -0.14391156831212787f); // -ln(1e4)/64
  const int s0 = r0 & 1023;
#pragma unroll
  for (int r = 0; r < 8; ++r) {
    const int row = wv * 8 + r;
    const float ang = (float)(s0 + row) * freq;
    const float pe = (lane & 1) ? cosf(ang) : sinf(ang);
    hf[(size_t)(r0 + row) * 64 + lane] = acc[r] + bcol + pe;
  }
}

// ---- 2: qkv -> qH/qL,kH/kL [bh][s][32] ; vtH/vtL [bh][32][1024]. 384 thr ----
__global__ __launch_bounds__(384) void r2_qkv(const float* __restrict__ hf,
                                              const float* __restrict__ Wq,
                                              const float* __restrict__ bq,
                                              u16* __restrict__ qH, u16* __restrict__ qL,
                                              u16* __restrict__ kH, u16* __restrict__ kL,
                                              u16* __restrict__ vtH, u16* __restrict__ vtL) {
  __shared__ float hr[32][68];
  __shared__ u16 vbH[64][40];
  __shared__ u16 vbL[64][40];
  const int r0 = blockIdx.x * 32, t = threadIdx.x;
  const int g = t / 192, u = t - g * 192;     // g: row-group (0/1), u: output col 0..191
  for (int e = t; e < 2048; e += 384) {
    int r = e >> 6, k = e & 63;
    hr[r][k] = hf[(size_t)(r0 + r) * 64 + k];
  }
  __syncthreads();
  float acc[16];
  const float bias = bq[u];
#pragma unroll
  for (int r = 0; r < 16; ++r) acc[r] = bias;
  for (int k = 0; k < 64; k += 4) {
    float w0 = Wq[(size_t)k * 192 + u];
    float w1 = Wq[(size_t)(k + 1) * 192 + u];
    float w2 = Wq[(size_t)(k + 2) * 192 + u];
    float w3 = Wq[(size_t)(k + 3) * 192 + u];
#pragma unroll
    for (int r = 0; r < 16; ++r) {
      f32x4 hv = *(const f32x4*)&hr[g * 16 + r][k];
      acc[r] = fmaf(hv[0], w0, fmaf(hv[1], w1, fmaf(hv[2], w2, fmaf(hv[3], w3, acc[r]))));
    }
  }
  const int which = u >> 6, c = u & 63, h = c >> 5, dh = c & 31;
  const int b = r0 >> 10, s0 = r0 & 1023;
  const size_t bh = (size_t)(b * 2 + h);
#pragma unroll
  for (int r = 0; r < 16; ++r) {
    const int row = g * 16 + r;
    const int s = s0 + row;
    u16 hi = f2bf(acc[r]);
    u16 lo = f2bf(acc[r] - bf2f(hi));
    if (which == 0)      { qH[(bh * 1024 + s) * 32 + dh] = hi; qL[(bh * 1024 + s) * 32 + dh] = lo; }
    else if (which == 1) { kH[(bh * 1024 + s) * 32 + dh] = hi; kL[(bh * 1024 + s) * 32 + dh] = lo; }
    else                 { vbH[c][row] = hi; vbL[c][row] = lo; }
  }
  __syncthreads();
  if (t < 128) {
    const int hh = (t & 63) >> 5, dh2 = t & 31;
    const size_t vb = ((size_t)(b * 2 + hh) * 32 + dh2) * 1024 + s0;
    const u16* src = (t < 64) ? &vbH[(t & 63)][0] : &vbL[(t & 63)][0];
    u16* dst = (t < 64) ? vtH : vtL;
#pragma unroll
    for (int i = 0; i < 2; ++i) {
      bf16x8 v = *(const bf16x8*)&src[i * 16];
      bf16x8 w = *(const bf16x8*)&src[i * 16 + 8];
      *(bf16x8*)&dst[vb + i * 16] = v;
      *(bf16x8*)&dst[vb + i * 16 + 8] = w;
    }
  }
}

// ---- 3: FUSED attention (round-14 form: LDS-staged dense nt stores) ----
__global__ __launch_bounds__(512, 4) void r3_fa(const u16* __restrict__ qH, const u16* __restrict__ qL,
                                                const u16* __restrict__ kH, const u16* __restrict__ kL,
                                                const u16* __restrict__ vtH, const u16* __restrict__ vtL,
                                                float* __restrict__ attn, float* __restrict__ ctx) {
  __shared__ __align__(16) char smem[33792];
  u16* pb = (u16*)smem;                        // [16][1024] bf16 P, swizzled (32 KB)
  float* redm = (float*)(smem + 32768);
  float* reds = (float*)(smem + 33280);
  float* part = (float*)smem;                  // aliased over pb after PV

  const int bid = blockIdx.x;
  const int wid = (bid & 7) * 1024 + (bid >> 3);
  const int bh = wid >> 6, qt = wid & 63;
  const int t = threadIdx.x, lane = t & 63, wv = t >> 6;
  const int fr = lane & 15, rg = lane >> 4, koff = rg * 8;
  const int i0 = qt * 16;
  const float scale = 0.17677669529663687f; // 1/sqrt(32)

  const size_t qoff = ((size_t)bh * 1024 + i0 + fr) * 32 + koff;
  bf16x8 aqh = *(const bf16x8*)&qH[qoff];
  bf16x8 aql = *(const bf16x8*)&qL[qoff];

  // QK^T: wave wv owns k-cols [wv*128, wv*128+128)
  f32x4 s[8];
#pragma unroll
  for (int jl = 0; jl < 8; ++jl) {
    const int jt = wv * 8 + jl;
    const size_t kof = ((size_t)bh * 1024 + jt * 16 + fr) * 32 + koff;
    bf16x8 bkh = *(const bf16x8*)&kH[kof];
    bf16x8 bkl = *(const bf16x8*)&kL[kof];
    f32x4 a = {};
    a = MFMA(aqh, bkh, a, 0, 0, 0);
    a = MFMA(aqh, bkl, a, 0, 0, 0);
    a = MFMA(aql, bkh, a, 0, 0, 0);
#pragma unroll
    for (int r = 0; r < 4; ++r) s[jl][r] = a[r] * scale;
  }

  // split-k softmax across 8 waves
  float m4[4];
#pragma unroll
  for (int r = 0; r < 4; ++r) m4[r] = s[0][r];
#pragma unroll
  for (int jl = 1; jl < 8; ++jl)
#pragma unroll
    for (int r = 0; r < 4; ++r) m4[r] = fmaxf(m4[r], s[jl][r]);
#pragma unroll
  for (int off = 1; off < 16; off <<= 1)
#pragma unroll
    for (int r = 0; r < 4; ++r) m4[r] = fmaxf(m4[r], __shfl_xor(m4[r], off));
  if (fr == 0) {
#pragma unroll
    for (int r = 0; r < 4; ++r) redm[wv * 16 + rg * 4 + r] = m4[r];
  }
  __syncthreads();
  float mg[4];
#pragma unroll
  for (int r = 0; r < 4; ++r) {
    const int row = rg * 4 + r;
    float m = redm[row];
#pragma unroll
    for (int w = 1; w < 8; ++w) m = fmaxf(m, redm[w * 16 + row]);
    mg[r] = m;
  }
  float s4[4] = {0.f, 0.f, 0.f, 0.f};
#pragma unroll
  for (int jl = 0; jl < 8; ++jl)
#pragma unroll
    for (int r = 0; r < 4; ++r) { s[jl][r] = __expf(s[jl][r] - mg[r]); s4[r] += s[jl][r]; }
#pragma unroll
  for (int off = 1; off < 16; off <<= 1)
#pragma unroll
    for (int r = 0; r < 4; ++r) s4[r] += __shfl_xor(s4[r], off);
  if (fr == 0) {
#pragma unroll
    for (int r = 0; r < 4; ++r) reds[wv * 16 + rg * 4 + r] = s4[r];
  }
  __syncthreads();
  float inv[4];
#pragma unroll
  for (int r = 0; r < 4; ++r) {
    const int row = rg * 4 + r;
    float ssum = reds[row];
#pragma unroll
    for (int w = 1; w < 8; ++w) ssum += reds[w * 16 + row];
    inv[r] = 1.f / ssum;
  }

  // P -> bf16 LDS (swizzled: col ^ ((row>>2)<<4))
#pragma unroll
  for (int r = 0; r < 4; ++r) {
    const int row = rg * 4 + r;
    const int sw = rg << 4;
    const int rb = row * 1024;
#pragma unroll
    for (int jl = 0; jl < 8; ++jl) {
      const int col = (wv * 8 + jl) * 16 + fr;
      pb[rb + (col ^ sw)] = f2bf(s[jl][r] * inv[r]);
    }
  }
  __syncthreads();

  // DENSE coalesced nt attn write: thread t -> row t>>5, col (t&31)*4 + 128c
  {
    const int row = t >> 5, x32 = t & 31;
    const int sw = (row >> 2) << 4;
    const size_t gb = ((size_t)bh * 1024 + i0 + row) * 1024;
#pragma unroll
    for (int c = 0; c < 8; ++c) {
      const int col = x32 * 4 + 128 * c;
      bf16x4 v = *(const bf16x4*)&pb[row * 1024 + (col ^ sw)];
      f32x4 o;
#pragma unroll
      for (int i = 0; i < 4; ++i) o[i] = bf2f((u16)v[i]);
      __builtin_nontemporal_store(o, (f32x4*)&attn[gb + col]);
    }
  }

  // PV: wave wv handles k-tiles wv*4..wv*4+3
  const int sw2 = (fr >> 2) << 4;
  f32x4 acc2[2] = {};
#pragma unroll
  for (int i = 0; i < 4; ++i) {
    const int kt = wv * 4 + i;
    const int cb = kt * 32 + rg * 8;
    bf16x8 ph = *(const bf16x8*)&pb[fr * 1024 + (cb ^ sw2)];
#pragma unroll
    for (int nb = 0; nb < 2; ++nb) {
      const size_t vo = ((size_t)bh * 32 + nb * 16 + fr) * 1024 + cb;
      bf16x8 vh = *(const bf16x8*)&vtH[vo];
      bf16x8 vl = *(const bf16x8*)&vtL[vo];
      acc2[nb] = MFMA(ph, vh, acc2[nb], 0, 0, 0);
      acc2[nb] = MFMA(ph, vl, acc2[nb], 0, 0, 0);
    }
  }
  __syncthreads();
#pragma unroll
  for (int nb = 0; nb < 2; ++nb)
#pragma unroll
    for (int r = 0; r < 4; ++r)
      part[(wv * 16 + rg * 4 + r) * 32 + nb * 16 + fr] = acc2[nb][r];
  __syncthreads();
  const int b = bh >> 1, h = bh & 1;
  {
    const int row = t >> 5, dh = t & 31;
    float v = part[(row) * 32 + dh];
#pragma unroll
    for (int w = 1; w < 8; ++w) v += part[(w * 16 + row) * 32 + dh];
    ctx[((size_t)b * 1024 + i0 + row) * 64 + h * 32 + dh] = v;
  }
}

// ---- 4: FUSED ln1 + FF + ln2 + partial pool. 16 rows/block, 256 thr ----
__global__ __launch_bounds__(256) void r56_ln_ff(const float* __restrict__ ctx,
                                                 const float* __restrict__ Wo,
                                                 const float* __restrict__ bo,
                                                 const float* __restrict__ hf,
                                                 const float* __restrict__ g1,
                                                 const float* __restrict__ be1,
                                                 const float* __restrict__ W1,
                                                 const float* __restrict__ b1,
                                                 const float* __restrict__ W2,
                                                 const float* __restrict__ b2,
                                                 const float* __restrict__ g2,
                                                 const float* __restrict__ be2,
                                                 float* __restrict__ pp) {
  __shared__ __align__(16) char smem[38656];
  float* yr   = (float*)smem;
  float* fr   = (float*)(smem + 4352);
  float* part = (float*)(smem + 21248);
  float* cr   = (float*)(smem + 4352);
  float* wo   = (float*)(smem + 8704);
  float* pw   = (float*)(smem + 37632);
  const int r0 = blockIdx.x * 16;
  const int t = threadIdx.x, d = t & 63, wv = t >> 6;

  for (int e = t; e < 1024; e += 256) cr[(e >> 6) * 68 + (e & 63)] = ctx[(size_t)(r0 + (e >> 6)) * 64 + (e & 63)];
  for (int e = t; e < 4096; e += 256) wo[e] = Wo[e];
  __syncthreads();

  {
    float acc[4];
    const float bias = bo[d];
#pragma unroll
    for (int r = 0; r < 4; ++r) acc[r] = bias;
    for (int k = 0; k < 64; ++k) {
      const float w = wo[k * 64 + d];
#pragma unroll
      for (int r = 0; r < 4; ++r) acc[r] = fmaf(cr[(wv * 4 + r) * 68 + k], w, acc[r]);
    }
    const float gd = g1[d], bd = be1[d];
#pragma unroll
    for (int r = 0; r < 4; ++r) {
      const int row = wv * 4 + r;
      const float rv = hf[(size_t)(r0 + row) * 64 + d] + acc[r];
      const float mu = wred_sum(rv) * (1.f / 64.f);
      const float dd = rv - mu;
      const float var = wred_sum(dd * dd) * (1.f / 64.f);
      yr[row * 68 + d] = dd * rsqrtf(var + 1e-5f) * gd + bd;
    }
  }
  __syncthreads();

  {
    float acc[16];
    const float bias = b1[t];
#pragma unroll
    for (int r = 0; r < 16; ++r) acc[r] = bias;
    for (int k = 0; k < 64; k += 4) {
      float w0 = W1[(size_t)k * 256 + t];
      float w1 = W1[(size_t)(k + 1) * 256 + t];
      float w2 = W1[(size_t)(k + 2) * 256 + t];
      float w3 = W1[(size_t)(k + 3) * 256 + t];
#pragma unroll
      for (int r = 0; r < 16; ++r) {
        f32x4 yv = *(const f32x4*)&yr[r * 68 + k];
        acc[r] = fmaf(yv[0], w0, fmaf(yv[1], w1, fmaf(yv[2], w2, fmaf(yv[3], w3, acc[r]))));
      }
    }
#pragma unroll
    for (int r = 0; r < 16; ++r) fr[r * 264 + t] = fmaxf(acc[r], 0.f);
  }
  __syncthreads();

  {
    float acc[16];
#pragma unroll
    for (int r = 0; r < 16; ++r) acc[r] = 0.f;
    for (int kk = 0; kk < 64; kk += 4) {
      const int k = wv * 64 + kk;
      float w0 = W2[(size_t)k * 64 + d];
      float w1 = W2[(size_t)(k + 1) * 64 + d];
      float w2 = W2[(size_t)(k + 2) * 64 + d];
      float w3 = W2[(size_t)(k + 3) * 64 + d];
#pragma unroll
      for (int r = 0; r < 16; ++r) {
        f32x4 fv = *(const f32x4*)&fr[r * 264 + k];
        acc[r] = fmaf(fv[0], w0, fmaf(fv[1], w1, fmaf(fv[2], w2, fmaf(fv[3], w3, acc[r]))));
      }
    }
#pragma unroll
    for (int r = 0; r < 16; ++r) part[(wv * 16 + r) * 64 + d] = acc[r];
  }
  __syncthreads();

  {
    float pool = 0.f;
    const float bd2 = b2[d], gd = g2[d], bd = be2[d];
#pragma unroll
    for (int rr = 0; rr < 4; ++rr) {
      const int row = wv * 4 + rr;
      const float o2 = part[row * 64 + d] + part[(16 + row) * 64 + d] +
                       part[(32 + row) * 64 + d] + part[(48 + row) * 64 + d] + bd2;
      const float rv = yr[row * 68 + d] + o2;
      const float mu = wred_sum(rv) * (1.f / 64.f);
      const float dd = rv - mu;
      const float var = wred_sum(dd * dd) * (1.f / 64.f);
      pool += dd * rsqrtf(var + 1e-5f) * gd + bd;
    }
    pw[wv * 64 + d] = pool;
  }
  __syncthreads();
  if (t < 64) pp[(size_t)blockIdx.x * 64 + t] = pw[t] + pw[64 + t] + pw[128 + t] + pw[192 + t];
}

// ---- 5: reduce pool partials + classifier -> logits. 256 thr ----
__global__ __launch_bounds__(256) void r7_cls(const float* __restrict__ pp,
                                              const float* __restrict__ Wc1,
                                              const float* __restrict__ bc1,
                                              const float* __restrict__ Wc2,
                                              const float* __restrict__ bc2,
                                              float* __restrict__ outp) {
  __shared__ float red[4][64];
  const int b = blockIdx.x, t = threadIdx.x;
  const int lane = t & 63, wv = t >> 6;
  float po = 0.f;
  for (int i = wv; i < 64; i += 4) po += pp[(size_t)(b * 64 + i) * 64 + lane];
  red[wv][lane] = po;
  __syncthreads();
  if (wv == 0) {
    po = (red[0][lane] + red[1][lane] + red[2][lane] + red[3][lane]) * (1.f / 1024.f);
    float acc = bc1[lane];
    for (int k = 0; k < 64; ++k) acc = fmaf(__shfl(po, k), Wc1[(size_t)k * 64 + lane], acc);
    const float t1 = fmaxf(acc, 0.f);
    const float l0 = wred_sum(t1 * Wc2[(size_t)lane * 2 + 0]);
    const float l1 = wred_sum(t1 * Wc2[(size_t)lane * 2 + 1]);
    if (lane == 0) {
      outp[b * 2 + 0] = l0 + bc2[0];
      outp[b * 2 + 1] = l1 + bc2[1];
    }
  }
}

extern "C" void kernel_launch(void* const* d_in, const int* in_sizes, int n_in,
                              void* d_out, int out_size, void* d_ws, size_t ws_size,
                              hipStream_t stream) {
  (void)in_sizes; (void)n_in; (void)out_size; (void)ws_size;
  const float* x     = (const float*)d_in[0];
  const float* W_in  = (const float*)d_in[1];
  const float* b_in  = (const float*)d_in[2];
  const float* W_qkv = (const float*)d_in[3];
  const float* b_qkv = (const float*)d_in[4];
  const float* W_o   = (const float*)d_in[5];
  const float* b_o   = (const float*)d_in[6];
  const float* g1    = (const float*)d_in[7];
  const float* be1   = (const float*)d_in[8];
  const float* W1    = (const float*)d_in[9];
  const float* b1    = (const float*)d_in[10];
  const float* W2    = (const float*)d_in[11];
  const float* b2    = (const float*)d_in[12];
  const float* g2    = (const float*)d_in[13];
  const float* be2   = (const float*)d_in[14];
  const float* Wc1   = (const float*)d_in[15];
  const float* bc1   = (const float*)d_in[16];
  const float* Wc2   = (const float*)d_in[17];
  const float* bc2   = (const float*)d_in[18];

  char* ws = (char*)d_ws;
  const size_t SZF = (size_t)65536 * 64 * 4;       // 16.78 MB
  const size_t SZH = (size_t)128 * 1024 * 32 * 2;  //  8.39 MB
  float* hf  = (float*)(ws + 0);
  u16* qH    = (u16*)(ws + SZF);
  u16* qL    = (u16*)(ws + SZF + 1 * SZH);
  u16* kH    = (u16*)(ws + SZF + 2 * SZH);
  u16* kL    = (u16*)(ws + SZF + 3 * SZH);
  u16* vtH   = (u16*)(ws + SZF + 4 * SZH);
  u16* vtL   = (u16*)(ws + SZF + 5 * SZH);
  float* ctx = (float*)(ws + SZF + 6 * SZH);
  float* pp  = (float*)(ws + 2 * SZF + 6 * SZH);   // 1 MB

  float* outp = (float*)d_out;       // [logits 128 | attn] f32
  float* attn = outp + 128;

  r1_inproj<<<2048, 256, 0, stream>>>(x, W_in, b_in, hf);
  r2_qkv   <<<2048, 384, 0, stream>>>(hf, W_qkv, b_qkv, qH, qL, kH, kL, vtH, vtL);
  r3_fa    <<<8192, 512, 0, stream>>>(qH, qL, kH, kL, vtH, vtL, attn, ctx);
  r56_ln_ff<<<4096, 256, 0, stream>>>(ctx, W_o, b_o, hf, g1, be1, W1, b1, W2, b2, g2, be2, pp);
  r7_cls   <<<64, 256, 0, stream>>>(pp, Wc1, bc1, Wc2, bc2, outp);
}